// Round 5
// baseline (595.146 us; speedup 1.0000x reference)
//
#include <hip/hip_runtime.h>
#include <cstdint>
#include <cstddef>

#define BATCH 4
#define CCH   256
#define HW    4096
#define NM    4096
#define RB    32     // rows per k_fused block

typedef __attribute__((ext_vector_type(8))) short s16x8;
typedef __attribute__((ext_vector_type(4))) float f32x4;

__device__ __forceinline__ short f2bf(float f) {
    unsigned u = __float_as_uint(f);
    u += 0x7FFFu + ((u >> 16) & 1u);
    return (short)(u >> 16);
}
__device__ __forceinline__ float bf2f(short s) {
    return __uint_as_float(((unsigned)(unsigned short)s) << 16);
}

// ---------------------------------------------------------------------------
// k_cast: fp32 -> bf16, same layout. n multiple of 4. (weights only)
// ---------------------------------------------------------------------------
__global__ __launch_bounds__(256) void k_cast(const float* __restrict__ s,
                                              short* __restrict__ d, int n) {
    int i = (blockIdx.x * 256 + threadIdx.x) * 4;
    if (i + 3 < n) {
        float4 v = *(const float4*)&s[i];
        *(short4*)&d[i] = make_short4(f2bf(v.x), f2bf(v.y), f2bf(v.z), f2bf(v.w));
    }
}

// ---------------------------------------------------------------------------
// k_prep: one pass over in1/in2 producing BOTH direct bf16 (b,c,p) and
// transposed bf16 (b,p,c). grid (HW/64, CCH/64, 8): z = b*2+which.
// ---------------------------------------------------------------------------
__global__ __launch_bounds__(256) void k_prep(const float* __restrict__ in1,
                                              const float* __restrict__ in2,
                                              short* __restrict__ X16,
                                              short* __restrict__ Q16,
                                              short* __restrict__ Xt16,
                                              short* __restrict__ Qt16) {
    __shared__ short S[64][72];
    int t = threadIdx.x;
    int p0 = blockIdx.x * 64, c0 = blockIdx.y * 64;
    int z = blockIdx.z;
    int b = z >> 1, which = z & 1;
    const float* src = (which ? in2 : in1) + (size_t)b * CCH * HW;
    short* direct = (which ? Q16 : X16) + (size_t)b * CCH * HW;
    short* trans  = (which ? Qt16 : Xt16) + (size_t)b * HW * CCH;
    int tx = t & 15, ty = t >> 4;
#pragma unroll
    for (int i = 0; i < 4; ++i) {
        int c = ty + i * 16;
        float4 v = *(const float4*)&src[(size_t)(c0 + c) * HW + p0 + tx * 4];
        short4 h = make_short4(f2bf(v.x), f2bf(v.y), f2bf(v.z), f2bf(v.w));
        *(short4*)&direct[(size_t)(c0 + c) * HW + p0 + tx * 4] = h;
        S[tx * 4 + 0][c] = h.x;
        S[tx * 4 + 1][c] = h.y;
        S[tx * 4 + 2][c] = h.z;
        S[tx * 4 + 3][c] = h.w;
    }
    __syncthreads();
#pragma unroll
    for (int i = 0; i < 4; ++i) {
        int p = ty + i * 16;
        short4 v = *(const short4*)&S[p][tx * 4];
        *(short4*)&trans[(size_t)(p0 + p) * CCH + c0 + tx * 4] = v;
    }
}

// ---------------------------------------------------------------------------
// k_E_mfma: E16n[b,n,d] = bf16( sum_c Xt16[b,n,c] * We16[d,c] )
// TM=128(n), TN=128(d), BK=64, K=256. grid (2, 32, B), block 256.
// ---------------------------------------------------------------------------
__global__ __launch_bounds__(256) void k_E_mfma(const short* __restrict__ Xt16,
                                                const short* __restrict__ We16,
                                                short* __restrict__ E16n) {
    __shared__ short As[128 * 72];
    __shared__ short Bs[128 * 72];
    int t = threadIdx.x;
    int d0 = blockIdx.x * 128, n0 = blockIdx.y * 128, b = blockIdx.z;
    const short* Xb = Xt16 + (size_t)b * HW * CCH;
    short* Eb = E16n + (size_t)b * HW * CCH;
    int lm = t & 15, q = (t >> 4) & 3, w = t >> 6;
    int wr = (w >> 1) * 64, wc = (w & 1) * 64;
    f32x4 acc[4][4];
#pragma unroll
    for (int i = 0; i < 4; ++i)
#pragma unroll
        for (int j = 0; j < 4; ++j) acc[i][j] = (f32x4){0.f, 0.f, 0.f, 0.f};

    for (int k0 = 0; k0 < CCH; k0 += 64) {
#pragma unroll
        for (int u = 0; u < 4; ++u) {
            int chunk = t + u * 256;
            int row = chunk >> 3, off = (chunk & 7) * 8;
            *(float4*)&As[row * 72 + off] =
                *(const float4*)&Xb[(size_t)(n0 + row) * CCH + k0 + off];
            *(float4*)&Bs[row * 72 + off] =
                *(const float4*)&We16[(size_t)(d0 + row) * CCH + k0 + off];
        }
        __syncthreads();
#pragma unroll
        for (int kk = 0; kk < 2; ++kk) {
            s16x8 af[4], bfr[4];
#pragma unroll
            for (int i = 0; i < 4; ++i)
                af[i] = *(const s16x8*)&As[(wr + i * 16 + lm) * 72 + kk * 32 + q * 8];
#pragma unroll
            for (int j = 0; j < 4; ++j)
                bfr[j] = *(const s16x8*)&Bs[(wc + j * 16 + lm) * 72 + kk * 32 + q * 8];
#pragma unroll
            for (int i = 0; i < 4; ++i)
#pragma unroll
                for (int j = 0; j < 4; ++j)
                    acc[i][j] = __builtin_amdgcn_mfma_f32_16x16x32_bf16(
                        af[i], bfr[j], acc[i][j], 0, 0, 0);
        }
        __syncthreads();
    }
#pragma unroll
    for (int i = 0; i < 4; ++i)
#pragma unroll
        for (int r = 0; r < 4; ++r) {
            size_t base = (size_t)(n0 + wr + i * 16 + q * 4 + r) * CCH;
#pragma unroll
            for (int j = 0; j < 4; ++j)
                Eb[base + d0 + wc + j * 16 + lm] = f2bf(acc[i][j][r]);
        }
}

// ---------------------------------------------------------------------------
// k_fused v2: flash-style fused score->exp->PV, 32 rows/block.
// which=0 (eatt rows n): Ar=E16n, Ac=Qt16, V=Q16.
// which=1 (qatt rows m): Ar=Qt16, Ac=E16n, V=X16.
// Ar preloaded to LDS once; Ac and V fragments read DIRECTLY from global
// (L2-resident per XCD via blockIdx%8 unit mapping). 2 barriers per col-tile.
// grid (1024), block 256, 4 blocks/CU.
// ---------------------------------------------------------------------------
__global__ __launch_bounds__(256, 4) void k_fused(const short* __restrict__ E16n,
                                                  const short* __restrict__ Qt16,
                                                  const short* __restrict__ Q16,
                                                  const short* __restrict__ X16,
                                                  short* __restrict__ eattT,
                                                  short* __restrict__ qattT) {
    __shared__ short ArS[RB * 264];   // 16.9 KB, stride 132 dw (uniform banks)
    __shared__ short Ps[RB * 136];    // 8.7 KB, stride 68 dw (uniform banks)
    __shared__ float rs[4 * RB];      // 0.5 KB

    int t = threadIdx.x;
    int gid = blockIdx.x;
    int unit = gid & 7;
    int b = unit >> 1, which = unit & 1;
    int r0 = (gid >> 3) * RB;

    const short* Ar = (which ? Qt16 : E16n) + (size_t)b * HW * CCH;
    const short* Ac = (which ? E16n : Qt16) + (size_t)b * HW * CCH;
    const short* V  = (which ? X16  : Q16 ) + (size_t)b * CCH * HW;
    short* Out = (which ? qattT : eattT) + (size_t)b * HW * CCH;

    int lm = t & 15, q = (t >> 4) & 3, w = t >> 6;
    int wqs = w * 32;   // this wave's score-column quarter (of 128)
    int cq  = w * 64;   // this wave's V-channel quarter (of 256)

    // ---- preload Ar rows [r0, r0+32) x K=256 into LDS (once)
#pragma unroll
    for (int u = 0; u < 4; ++u) {
        int chunk = t + u * 256;
        int row = chunk >> 5, off = (chunk & 31) * 8;
        *(float4*)&ArS[row * 264 + off] =
            *(const float4*)&Ar[(size_t)(r0 + row) * CCH + off];
    }
    __syncthreads();

    f32x4 oacc[2][4];
    float rsum[2][4];
#pragma unroll
    for (int i = 0; i < 2; ++i) {
#pragma unroll
        for (int j = 0; j < 4; ++j) oacc[i][j] = (f32x4){0.f, 0.f, 0.f, 0.f};
#pragma unroll
        for (int r = 0; r < 4; ++r) rsum[i][r] = 0.f;
    }

    for (int col0 = 0; col0 < NM; col0 += 128) {
        // ---- score: S[32][128] = Ar . Ac[col0:+128]^T  (no barriers)
        f32x4 sacc[2][2];
#pragma unroll
        for (int i = 0; i < 2; ++i)
#pragma unroll
            for (int j = 0; j < 2; ++j) sacc[i][j] = (f32x4){0.f, 0.f, 0.f, 0.f};
#pragma unroll
        for (int kk = 0; kk < 8; ++kk) {
            s16x8 af[2], bf[2];
#pragma unroll
            for (int i = 0; i < 2; ++i)
                af[i] = *(const s16x8*)&ArS[(i * 16 + lm) * 264 + kk * 32 + q * 8];
#pragma unroll
            for (int j = 0; j < 2; ++j)
                bf[j] = *(const s16x8*)&Ac[(size_t)(col0 + wqs + j * 16 + lm) * CCH +
                                           kk * 32 + q * 8];
#pragma unroll
            for (int i = 0; i < 2; ++i)
#pragma unroll
                for (int j = 0; j < 2; ++j)
                    sacc[i][j] = __builtin_amdgcn_mfma_f32_16x16x32_bf16(
                        af[i], bf[j], sacc[i][j], 0, 0, 0);
        }
        __syncthreads();   // previous tile's PV reads of Ps are done
        // ---- exp + P-tile to LDS + rowsum
#pragma unroll
        for (int i = 0; i < 2; ++i)
#pragma unroll
            for (int j = 0; j < 2; ++j)
#pragma unroll
                for (int r = 0; r < 4; ++r) {
                    float v = __expf(sacc[i][j][r]);
                    short h = f2bf(v);
                    rsum[i][r] += bf2f(h);
                    Ps[(i * 16 + q * 4 + r) * 136 + wqs + j * 16 + lm] = h;
                }
        __syncthreads();   // Ps visible to all waves
        // ---- PV: oacc += P[:, col-tile] . V[:, col-tile]^T
#pragma unroll
        for (int km = 0; km < 4; ++km) {
            s16x8 pf[2], vf[4];
#pragma unroll
            for (int i = 0; i < 2; ++i)
                pf[i] = *(const s16x8*)&Ps[(i * 16 + lm) * 136 + km * 32 + q * 8];
#pragma unroll
            for (int j = 0; j < 4; ++j)
                vf[j] = *(const s16x8*)&V[(size_t)(cq + j * 16 + lm) * HW +
                                          col0 + km * 32 + q * 8];
#pragma unroll
            for (int i = 0; i < 2; ++i)
#pragma unroll
                for (int j = 0; j < 4; ++j)
                    oacc[i][j] = __builtin_amdgcn_mfma_f32_16x16x32_bf16(
                        pf[i], vf[j], oacc[i][j], 0, 0, 0);
        }
    }

    // ---- rowsum reduce: over lm lanes, then across waves via LDS
#pragma unroll
    for (int i = 0; i < 2; ++i)
#pragma unroll
        for (int r = 0; r < 4; ++r) {
            float s = rsum[i][r];
            s += __shfl_xor(s, 1, 64);
            s += __shfl_xor(s, 2, 64);
            s += __shfl_xor(s, 4, 64);
            s += __shfl_xor(s, 8, 64);
            if (lm == 0) rs[w * RB + i * 16 + q * 4 + r] = s;
        }
    __syncthreads();
#pragma unroll
    for (int i = 0; i < 2; ++i)
#pragma unroll
        for (int r = 0; r < 4; ++r) {
            int row = i * 16 + q * 4 + r;
            float inv = 1.f / (rs[row] + rs[RB + row] + rs[2 * RB + row] +
                               rs[3 * RB + row]);
            size_t base = (size_t)(r0 + row) * CCH;
#pragma unroll
            for (int j = 0; j < 4; ++j)
                Out[base + cq + j * 16 + lm] = f2bf(oacc[i][j][r] * inv);
        }
}

// ---------------------------------------------------------------------------
// k_gate: m[b,p] = sigmoid( sum_c attT[b,p,c]*gw[c] ). grid (B*HW/16, 2)
// ---------------------------------------------------------------------------
__global__ __launch_bounds__(256) void k_gate(const short* __restrict__ eattT,
                                              const short* __restrict__ qattT,
                                              const float* __restrict__ gw,
                                              float* __restrict__ m1,
                                              float* __restrict__ m2) {
    int t = threadIdx.x;
    int which = blockIdx.y;
    const short* att = which ? qattT : eattT;
    float* dst = which ? m2 : m1;
    size_t pg = (size_t)blockIdx.x * 16 + (t >> 4);
    int sub = t & 15;
    const short* rowp = att + pg * CCH + sub * 16;
    float s = 0.f;
#pragma unroll
    for (int k = 0; k < 16; ++k) s = fmaf(bf2f(rowp[k]), gw[sub * 16 + k], s);
    s += __shfl_xor(s, 1, 64);
    s += __shfl_xor(s, 2, 64);
    s += __shfl_xor(s, 4, 64);
    s += __shfl_xor(s, 8, 64);
    if (sub == 0) dst[pg] = 1.f / (1.f + __expf(-s));
}

// ---------------------------------------------------------------------------
// k_final (merged): half = blockIdx.z>>2 selects (W1,eattT,Xt16,m1,out1) vs
// (W2,qattT,Qt16,m2,out2). TM=128(o), TN=64(p), BK=32, two K=256 phases.
// grid (64, 2, 8), block 256.
// ---------------------------------------------------------------------------
__global__ __launch_bounds__(256) void k_final(const short* __restrict__ W16_1,
                                               const short* __restrict__ W16_2,
                                               const short* __restrict__ eattT,
                                               const short* __restrict__ qattT,
                                               const short* __restrict__ Xt16,
                                               const short* __restrict__ Qt16,
                                               const float* __restrict__ m1v,
                                               const float* __restrict__ m2v,
                                               float* __restrict__ outbase) {
    __shared__ short As[128 * 40];
    __shared__ short Bs[64 * 40];
    int t = threadIdx.x;
    int zz = blockIdx.z;
    int half = zz >> 2, b = zz & 3;
    const short* W16 = half ? W16_2 : W16_1;
    const short* attT = (half ? qattT : eattT);
    const short* inT  = (half ? Qt16 : Xt16);
    const float* gate = half ? m2v : m1v;
    float* outp = outbase + (size_t)half * BATCH * CCH * HW;
    int p0 = blockIdx.x * 64, o0 = blockIdx.y * 128;
    const short* Tb0 = attT + (size_t)b * HW * CCH;
    const short* Tb1 = inT + (size_t)b * HW * CCH;
    int lm = t & 15, q = (t >> 4) & 3, w = t >> 6;
    int wr = (w >> 1) * 64, wc = (w & 1) * 32;
    f32x4 acc[2][4][2];
#pragma unroll
    for (int ph = 0; ph < 2; ++ph)
#pragma unroll
        for (int i = 0; i < 4; ++i)
#pragma unroll
            for (int j = 0; j < 2; ++j) acc[ph][i][j] = (f32x4){0.f, 0.f, 0.f, 0.f};

    int brow = t >> 2, boff = (t & 3) * 8;
    for (int ph = 0; ph < 2; ++ph) {
        const short* Tb = ph ? Tb1 : Tb0;
        for (int k0 = 0; k0 < CCH; k0 += 32) {
#pragma unroll
            for (int u = 0; u < 2; ++u) {
                int chunk = t + u * 256;
                int row = chunk >> 2, off = (chunk & 3) * 8;
                *(float4*)&As[row * 40 + off] =
                    *(const float4*)&W16[(size_t)(o0 + row) * 512 + ph * 256 + k0 + off];
            }
            *(float4*)&Bs[brow * 40 + boff] =
                *(const float4*)&Tb[(size_t)(p0 + brow) * CCH + k0 + boff];
            __syncthreads();
            s16x8 af[4], bfr[2];
#pragma unroll
            for (int i = 0; i < 4; ++i)
                af[i] = *(const s16x8*)&As[(wr + i * 16 + lm) * 40 + q * 8];
#pragma unroll
            for (int j = 0; j < 2; ++j)
                bfr[j] = *(const s16x8*)&Bs[(wc + j * 16 + lm) * 40 + q * 8];
#pragma unroll
            for (int i = 0; i < 4; ++i)
#pragma unroll
                for (int j = 0; j < 2; ++j)
                    acc[ph][i][j] = __builtin_amdgcn_mfma_f32_16x16x32_bf16(
                        af[i], bfr[j], acc[ph][i][j], 0, 0, 0);
            __syncthreads();
        }
    }
#pragma unroll
    for (int j = 0; j < 2; ++j) {
        int p = p0 + wc + j * 16 + lm;
        float gv = gate[(size_t)b * HW + p];
#pragma unroll
        for (int i = 0; i < 4; ++i)
#pragma unroll
            for (int r = 0; r < 4; ++r) {
                int o = o0 + wr + i * 16 + q * 4 + r;
                outp[((size_t)b * CCH + o) * HW + p] =
                    acc[0][i][j][r] * gv + acc[1][i][j][r];
            }
    }
}

// ---------------------------------------------------------------------------
extern "C" void kernel_launch(void* const* d_in, const int* in_sizes, int n_in,
                              void* d_out, int out_size, void* d_ws, size_t ws_size,
                              hipStream_t stream) {
    (void)in_sizes; (void)n_in; (void)out_size; (void)ws_size;
    const float* in1 = (const float*)d_in[0];
    const float* in2 = (const float*)d_in[1];
    const float* We  = (const float*)d_in[2];
    const float* gw  = (const float*)d_in[3];
    const float* W1  = (const float*)d_in[4];
    const float* W2  = (const float*)d_in[5];
    float* out = (float*)d_out;
    char* ws = (char*)d_ws;

    const size_t SB = (size_t)BATCH * CCH * HW * 2;    // 8 MB bf16 tensor
    const size_t WB = (size_t)CCH * 2 * CCH * 2;       // 256 KB
    const size_t EB = (size_t)CCH * CCH * 2;           // 128 KB (We16)
    const size_t VB = (size_t)BATCH * NM * 4;          // 64 KB

    size_t off = 0;
    auto alloc = [&](size_t bytes) {
        char* p = ws + off;
        off += (bytes + 255) & ~(size_t)255;
        return p;
    };
    short* W16_1 = (short*)alloc(WB);
    short* W16_2 = (short*)alloc(WB);
    short* We16  = (short*)alloc(EB);
    short* Xt16  = (short*)alloc(SB);   // in1^T (b,p,c)
    short* Qt16  = (short*)alloc(SB);   // in2^T (b,p,c)
    short* E16n  = (short*)alloc(SB);   // (b,n,d)
    short* eattT = (short*)alloc(SB);
    short* qattT = (short*)alloc(SB);
    short* X16   = (short*)alloc(SB);   // in1 (b,c,p) bf16
    short* Q16   = (short*)alloc(SB);   // in2 (b,c,p) bf16
    float* m1v   = (float*)alloc(VB);
    float* m2v   = (float*)alloc(VB);

    const int nW = CCH * 2 * CCH;
    const int nWe = CCH * CCH;

    k_cast<<<dim3(nW / 1024), 256, 0, stream>>>(W1, W16_1, nW);
    k_cast<<<dim3(nW / 1024), 256, 0, stream>>>(W2, W16_2, nW);
    k_cast<<<dim3(nWe / 1024), 256, 0, stream>>>(We, We16, nWe);
    k_prep<<<dim3(HW / 64, CCH / 64, 8), 256, 0, stream>>>(in1, in2, X16, Q16,
                                                           Xt16, Qt16);

    k_E_mfma<<<dim3(2, 32, BATCH), 256, 0, stream>>>(Xt16, We16, E16n);

    k_fused<<<dim3((HW / RB) * 8), 256, 0, stream>>>(E16n, Qt16, Q16, X16,
                                                     eattT, qattT);

    k_gate<<<dim3((BATCH * HW) / 16, 2), 256, 0, stream>>>(eattT, qattT, gw, m1v, m2v);
    k_final<<<dim3(64, 2, 8), 256, 0, stream>>>(W16_1, W16_2, eattT, qattT,
                                                Xt16, Qt16, m1v, m2v, out);
}

// Round 6
// 391.670 us; speedup vs baseline: 1.5195x; 1.5195x over previous
//
#include <hip/hip_runtime.h>
#include <cstdint>
#include <cstddef>

#define BATCH 4
#define CCH   256
#define HW    4096
#define NM    4096

typedef __attribute__((ext_vector_type(8))) short s16x8;
typedef __attribute__((ext_vector_type(4))) float f32x4;

__device__ __forceinline__ short f2bf(float f) {
    unsigned u = __float_as_uint(f);
    u += 0x7FFFu + ((u >> 16) & 1u);
    return (short)(u >> 16);
}
__device__ __forceinline__ float bf2f(short s) {
    return __uint_as_float(((unsigned)(unsigned short)s) << 16);
}

// ---------------------------------------------------------------------------
// k_cast: fp32 -> bf16, same layout (weights only).
// ---------------------------------------------------------------------------
__global__ __launch_bounds__(256) void k_cast(const float* __restrict__ s,
                                              short* __restrict__ d, int n) {
    int i = (blockIdx.x * 256 + threadIdx.x) * 4;
    if (i + 3 < n) {
        float4 v = *(const float4*)&s[i];
        *(short4*)&d[i] = make_short4(f2bf(v.x), f2bf(v.y), f2bf(v.z), f2bf(v.w));
    }
}

// ---------------------------------------------------------------------------
// k_prep: one pass over in1/in2 producing direct bf16 (b,c,p) and transposed
// bf16 (b,p,c). grid (HW/64, CCH/64, 8): z = b*2+which.
// ---------------------------------------------------------------------------
__global__ __launch_bounds__(256) void k_prep(const float* __restrict__ in1,
                                              const float* __restrict__ in2,
                                              short* __restrict__ X16,
                                              short* __restrict__ Q16,
                                              short* __restrict__ Xt16,
                                              short* __restrict__ Qt16) {
    __shared__ short S[64][72];
    int t = threadIdx.x;
    int p0 = blockIdx.x * 64, c0 = blockIdx.y * 64;
    int z = blockIdx.z;
    int b = z >> 1, which = z & 1;
    const float* src = (which ? in2 : in1) + (size_t)b * CCH * HW;
    short* direct = (which ? Q16 : X16) + (size_t)b * CCH * HW;
    short* trans  = (which ? Qt16 : Xt16) + (size_t)b * HW * CCH;
    int tx = t & 15, ty = t >> 4;
#pragma unroll
    for (int i = 0; i < 4; ++i) {
        int c = ty + i * 16;
        float4 v = *(const float4*)&src[(size_t)(c0 + c) * HW + p0 + tx * 4];
        short4 h = make_short4(f2bf(v.x), f2bf(v.y), f2bf(v.z), f2bf(v.w));
        *(short4*)&direct[(size_t)(c0 + c) * HW + p0 + tx * 4] = h;
        S[tx * 4 + 0][c] = h.x;
        S[tx * 4 + 1][c] = h.y;
        S[tx * 4 + 2][c] = h.z;
        S[tx * 4 + 3][c] = h.w;
    }
    __syncthreads();
#pragma unroll
    for (int i = 0; i < 4; ++i) {
        int p = ty + i * 16;
        short4 v = *(const short4*)&S[p][tx * 4];
        *(short4*)&trans[(size_t)(p0 + p) * CCH + c0 + tx * 4] = v;
    }
}

// ---------------------------------------------------------------------------
// k_E_mfma: E16n[b,n,d] = bf16( sum_c Xt16[b,n,c] * We16[d,c] )
// TM=128(n), TN=128(d), BK=64, K=256. grid (2, 32, B), block 256.
// ---------------------------------------------------------------------------
__global__ __launch_bounds__(256) void k_E_mfma(const short* __restrict__ Xt16,
                                                const short* __restrict__ We16,
                                                short* __restrict__ E16n) {
    __shared__ short As[128 * 72];
    __shared__ short Bs[128 * 72];
    int t = threadIdx.x;
    int d0 = blockIdx.x * 128, n0 = blockIdx.y * 128, b = blockIdx.z;
    const short* Xb = Xt16 + (size_t)b * HW * CCH;
    short* Eb = E16n + (size_t)b * HW * CCH;
    int lm = t & 15, q = (t >> 4) & 3, w = t >> 6;
    int wr = (w >> 1) * 64, wc = (w & 1) * 64;
    f32x4 acc[4][4];
#pragma unroll
    for (int i = 0; i < 4; ++i)
#pragma unroll
        for (int j = 0; j < 4; ++j) acc[i][j] = (f32x4){0.f, 0.f, 0.f, 0.f};

    for (int k0 = 0; k0 < CCH; k0 += 64) {
#pragma unroll
        for (int u = 0; u < 4; ++u) {
            int chunk = t + u * 256;
            int row = chunk >> 3, off = (chunk & 7) * 8;
            *(float4*)&As[row * 72 + off] =
                *(const float4*)&Xb[(size_t)(n0 + row) * CCH + k0 + off];
            *(float4*)&Bs[row * 72 + off] =
                *(const float4*)&We16[(size_t)(d0 + row) * CCH + k0 + off];
        }
        __syncthreads();
#pragma unroll
        for (int kk = 0; kk < 2; ++kk) {
            s16x8 af[4], bfr[4];
#pragma unroll
            for (int i = 0; i < 4; ++i)
                af[i] = *(const s16x8*)&As[(wr + i * 16 + lm) * 72 + kk * 32 + q * 8];
#pragma unroll
            for (int j = 0; j < 4; ++j)
                bfr[j] = *(const s16x8*)&Bs[(wc + j * 16 + lm) * 72 + kk * 32 + q * 8];
#pragma unroll
            for (int i = 0; i < 4; ++i)
#pragma unroll
                for (int j = 0; j < 4; ++j)
                    acc[i][j] = __builtin_amdgcn_mfma_f32_16x16x32_bf16(
                        af[i], bfr[j], acc[i][j], 0, 0, 0);
        }
        __syncthreads();
    }
#pragma unroll
    for (int i = 0; i < 4; ++i)
#pragma unroll
        for (int r = 0; r < 4; ++r) {
            size_t base = (size_t)(n0 + wr + i * 16 + q * 4 + r) * CCH;
#pragma unroll
            for (int j = 0; j < 4; ++j)
                Eb[base + d0 + wc + j * 16 + lm] = f2bf(acc[i][j][r]);
        }
}

// ---------------------------------------------------------------------------
// k_fused v3: flash-style score->exp->PV + fused gate, 64 rows/block, 4 waves.
// which=0 (eatt rows n): Ar=E16n, Ac=Qt16, V=Q16, gate->m1v.
// which=1 (qatt rows m): Ar=Qt16, Ac=E16n, V=X16, gate->m2v.
// Ar in LDS once (2 of 8 k-chunks cached in regs). Ac/V fragments direct from
// global (L2-resident per XCD unit). 2 barriers/col-tile around Ps round-trip.
// grid (512), block 256, 2 blocks/CU.
// ---------------------------------------------------------------------------
__global__ __launch_bounds__(256, 2) void k_fused(const short* __restrict__ E16n,
                                                  const short* __restrict__ Qt16,
                                                  const short* __restrict__ Q16,
                                                  const short* __restrict__ X16,
                                                  const float* __restrict__ gw,
                                                  short* __restrict__ eattT,
                                                  short* __restrict__ qattT,
                                                  float* __restrict__ m1v,
                                                  float* __restrict__ m2v) {
    __shared__ short ArS[64 * 264];   // 33.8 KB (132 dw stride; mod-32 = 4: 2-way ok)
    __shared__ short Ps[64 * 136];    // 17.4 KB (68 dw stride)
    __shared__ float rs[4 * 64];      // rowsum cross-wave
    __shared__ float grs[4 * 64];     // gate-dot cross-wave

    int t = threadIdx.x;
    int gid = blockIdx.x;
    int unit = gid & 7;
    int b = unit >> 1, which = unit & 1;
    int r0 = (gid >> 3) * 64;

    const short* Ar = (which ? Qt16 : E16n) + (size_t)b * HW * CCH;
    const short* Ac = (which ? E16n : Qt16) + (size_t)b * HW * CCH;
    const short* V  = (which ? X16  : Q16 ) + (size_t)b * CCH * HW;
    short* Out = (which ? qattT : eattT) + (size_t)b * HW * CCH;
    float* mdst = (which ? m2v : m1v) + (size_t)b * HW;

    int lm = t & 15, q = (t >> 4) & 3, w = t >> 6;
    int wqs = w * 32;   // this wave's score-column quarter (of 128)
    int cq  = w * 64;   // this wave's V-channel quarter (of 256)

    // gate weights for this lane's 4 channels
    float gwv[4];
#pragma unroll
    for (int j = 0; j < 4; ++j) gwv[j] = gw[cq + j * 16 + lm];

    // ---- preload Ar rows [r0, r0+64) x K=256 into LDS (once)
#pragma unroll
    for (int u = 0; u < 8; ++u) {
        int chunk = t + u * 256;
        int row = chunk >> 5, off = (chunk & 31) * 8;
        *(float4*)&ArS[row * 264 + off] =
            *(const float4*)&Ar[(size_t)(r0 + row) * CCH + off];
    }
    __syncthreads();

    // register-cache first 2 of 8 k-chunks of the Ar fragments (reduces LDS pipe)
    s16x8 afc[2][4];
#pragma unroll
    for (int kk = 0; kk < 2; ++kk)
#pragma unroll
        for (int i = 0; i < 4; ++i)
            afc[kk][i] = *(const s16x8*)&ArS[(i * 16 + lm) * 264 + kk * 32 + q * 8];

    f32x4 oacc[4][4];
    float rsum[4][4];
#pragma unroll
    for (int i = 0; i < 4; ++i) {
#pragma unroll
        for (int j = 0; j < 4; ++j) oacc[i][j] = (f32x4){0.f, 0.f, 0.f, 0.f};
#pragma unroll
        for (int r = 0; r < 4; ++r) rsum[i][r] = 0.f;
    }

    for (int col0 = 0; col0 < NM; col0 += 128) {
        // ---- score: S[64][128] = Ar . Ac[col0:+128]^T  (barrier-free)
        f32x4 sacc[4][2];
#pragma unroll
        for (int i = 0; i < 4; ++i)
#pragma unroll
            for (int j = 0; j < 2; ++j) sacc[i][j] = (f32x4){0.f, 0.f, 0.f, 0.f};
#pragma unroll
        for (int kk = 0; kk < 8; ++kk) {
            s16x8 af[4], bf[2];
#pragma unroll
            for (int i = 0; i < 4; ++i) {
                if (kk < 2) af[i] = afc[kk][i];
                else af[i] = *(const s16x8*)&ArS[(i * 16 + lm) * 264 + kk * 32 + q * 8];
            }
#pragma unroll
            for (int j = 0; j < 2; ++j)
                bf[j] = *(const s16x8*)&Ac[(size_t)(col0 + wqs + j * 16 + lm) * CCH +
                                           kk * 32 + q * 8];
#pragma unroll
            for (int i = 0; i < 4; ++i)
#pragma unroll
                for (int j = 0; j < 2; ++j)
                    sacc[i][j] = __builtin_amdgcn_mfma_f32_16x16x32_bf16(
                        af[i], bf[j], sacc[i][j], 0, 0, 0);
        }
        // ---- exp in registers (pre-barrier; bf16-rounded value kept in sacc)
#pragma unroll
        for (int i = 0; i < 4; ++i)
#pragma unroll
            for (int j = 0; j < 2; ++j)
#pragma unroll
                for (int r = 0; r < 4; ++r) {
                    float v = bf2f(f2bf(__expf(sacc[i][j][r])));
                    rsum[i][r] += v;
                    sacc[i][j][r] = v;
                }
        __syncthreads();   // A: previous tile's PV reads of Ps complete
#pragma unroll
        for (int i = 0; i < 4; ++i)
#pragma unroll
            for (int j = 0; j < 2; ++j)
#pragma unroll
                for (int r = 0; r < 4; ++r)
                    Ps[(i * 16 + q * 4 + r) * 136 + wqs + j * 16 + lm] =
                        (short)(__float_as_uint(sacc[i][j][r]) >> 16);
        __syncthreads();   // B: Ps visible
        // ---- PV: oacc += P[:, tile] . V[:, tile]^T
#pragma unroll
        for (int km = 0; km < 4; ++km) {
            s16x8 pf[4], vf[4];
#pragma unroll
            for (int j = 0; j < 4; ++j)
                vf[j] = *(const s16x8*)&V[(size_t)(cq + j * 16 + lm) * HW +
                                          col0 + km * 32 + q * 8];
#pragma unroll
            for (int i = 0; i < 4; ++i)
                pf[i] = *(const s16x8*)&Ps[(i * 16 + lm) * 136 + km * 32 + q * 8];
#pragma unroll
            for (int i = 0; i < 4; ++i)
#pragma unroll
                for (int j = 0; j < 4; ++j)
                    oacc[i][j] = __builtin_amdgcn_mfma_f32_16x16x32_bf16(
                        pf[i], vf[j], oacc[i][j], 0, 0, 0);
        }
    }

    // ---- rowsum reduce over lm lanes, then across waves
#pragma unroll
    for (int i = 0; i < 4; ++i)
#pragma unroll
        for (int r = 0; r < 4; ++r) {
            float s = rsum[i][r];
            s += __shfl_xor(s, 1, 64);
            s += __shfl_xor(s, 2, 64);
            s += __shfl_xor(s, 4, 64);
            s += __shfl_xor(s, 8, 64);
            if (lm == 0) rs[w * 64 + i * 16 + q * 4 + r] = s;
        }
    __syncthreads();

    // ---- normalize, store bf16 output, accumulate gate dot-product
    float gacc[4][4];
#pragma unroll
    for (int i = 0; i < 4; ++i)
#pragma unroll
        for (int r = 0; r < 4; ++r) {
            int row = i * 16 + q * 4 + r;
            float inv = 1.f / (rs[row] + rs[64 + row] + rs[128 + row] + rs[192 + row]);
            size_t base = (size_t)(r0 + row) * CCH;
            float ga = 0.f;
#pragma unroll
            for (int j = 0; j < 4; ++j) {
                short h = f2bf(oacc[i][j][r] * inv);
                Out[base + cq + j * 16 + lm] = h;
                ga = fmaf(bf2f(h), gwv[j], ga);
            }
            gacc[i][r] = ga;
        }
    // gate: reduce over lm, then across waves, sigmoid
#pragma unroll
    for (int i = 0; i < 4; ++i)
#pragma unroll
        for (int r = 0; r < 4; ++r) {
            float s = gacc[i][r];
            s += __shfl_xor(s, 1, 64);
            s += __shfl_xor(s, 2, 64);
            s += __shfl_xor(s, 4, 64);
            s += __shfl_xor(s, 8, 64);
            if (lm == 0) grs[w * 64 + i * 16 + q * 4 + r] = s;
        }
    __syncthreads();
    if (t < 64) {
        float g = grs[t] + grs[64 + t] + grs[128 + t] + grs[192 + t];
        mdst[r0 + t] = 1.f / (1.f + __expf(-g));
    }
}

// ---------------------------------------------------------------------------
// k_final (merged): half = blockIdx.z>>2 selects (W1,eattT,Xt16,m1,out1) vs
// (W2,qattT,Qt16,m2,out2). TM=128(o), TN=64(p), BK=32, two K=256 phases.
// grid (64, 2, 8), block 256.
// ---------------------------------------------------------------------------
__global__ __launch_bounds__(256) void k_final(const short* __restrict__ W16_1,
                                               const short* __restrict__ W16_2,
                                               const short* __restrict__ eattT,
                                               const short* __restrict__ qattT,
                                               const short* __restrict__ Xt16,
                                               const short* __restrict__ Qt16,
                                               const float* __restrict__ m1v,
                                               const float* __restrict__ m2v,
                                               float* __restrict__ outbase) {
    __shared__ short As[128 * 40];
    __shared__ short Bs[64 * 40];
    int t = threadIdx.x;
    int zz = blockIdx.z;
    int half = zz >> 2, b = zz & 3;
    const short* W16 = half ? W16_2 : W16_1;
    const short* attT = (half ? qattT : eattT);
    const short* inT  = (half ? Qt16 : Xt16);
    const float* gate = half ? m2v : m1v;
    float* outp = outbase + (size_t)half * BATCH * CCH * HW;
    int p0 = blockIdx.x * 64, o0 = blockIdx.y * 128;
    const short* Tb0 = attT + (size_t)b * HW * CCH;
    const short* Tb1 = inT + (size_t)b * HW * CCH;
    int lm = t & 15, q = (t >> 4) & 3, w = t >> 6;
    int wr = (w >> 1) * 64, wc = (w & 1) * 32;
    f32x4 acc[2][4][2];
#pragma unroll
    for (int ph = 0; ph < 2; ++ph)
#pragma unroll
        for (int i = 0; i < 4; ++i)
#pragma unroll
            for (int j = 0; j < 2; ++j) acc[ph][i][j] = (f32x4){0.f, 0.f, 0.f, 0.f};

    int brow = t >> 2, boff = (t & 3) * 8;
    for (int ph = 0; ph < 2; ++ph) {
        const short* Tb = ph ? Tb1 : Tb0;
        for (int k0 = 0; k0 < CCH; k0 += 32) {
#pragma unroll
            for (int u = 0; u < 2; ++u) {
                int chunk = t + u * 256;
                int row = chunk >> 2, off = (chunk & 3) * 8;
                *(float4*)&As[row * 40 + off] =
                    *(const float4*)&W16[(size_t)(o0 + row) * 512 + ph * 256 + k0 + off];
            }
            *(float4*)&Bs[brow * 40 + boff] =
                *(const float4*)&Tb[(size_t)(p0 + brow) * CCH + k0 + boff];
            __syncthreads();
            s16x8 af[4], bfr[2];
#pragma unroll
            for (int i = 0; i < 4; ++i)
                af[i] = *(const s16x8*)&As[(wr + i * 16 + lm) * 40 + q * 8];
#pragma unroll
            for (int j = 0; j < 2; ++j)
                bfr[j] = *(const s16x8*)&Bs[(wc + j * 16 + lm) * 40 + q * 8];
#pragma unroll
            for (int i = 0; i < 4; ++i)
#pragma unroll
                for (int j = 0; j < 2; ++j)
                    acc[ph][i][j] = __builtin_amdgcn_mfma_f32_16x16x32_bf16(
                        af[i], bfr[j], acc[ph][i][j], 0, 0, 0);
            __syncthreads();
        }
    }
#pragma unroll
    for (int j = 0; j < 2; ++j) {
        int p = p0 + wc + j * 16 + lm;
        float gv = gate[(size_t)b * HW + p];
#pragma unroll
        for (int i = 0; i < 4; ++i)
#pragma unroll
            for (int r = 0; r < 4; ++r) {
                int o = o0 + wr + i * 16 + q * 4 + r;
                outp[((size_t)b * CCH + o) * HW + p] =
                    acc[0][i][j][r] * gv + acc[1][i][j][r];
            }
    }
}

// ---------------------------------------------------------------------------
extern "C" void kernel_launch(void* const* d_in, const int* in_sizes, int n_in,
                              void* d_out, int out_size, void* d_ws, size_t ws_size,
                              hipStream_t stream) {
    (void)in_sizes; (void)n_in; (void)out_size; (void)ws_size;
    const float* in1 = (const float*)d_in[0];
    const float* in2 = (const float*)d_in[1];
    const float* We  = (const float*)d_in[2];
    const float* gw  = (const float*)d_in[3];
    const float* W1  = (const float*)d_in[4];
    const float* W2  = (const float*)d_in[5];
    float* out = (float*)d_out;
    char* ws = (char*)d_ws;

    const size_t SB = (size_t)BATCH * CCH * HW * 2;    // 8 MB bf16 tensor
    const size_t WB = (size_t)CCH * 2 * CCH * 2;       // 256 KB
    const size_t EB = (size_t)CCH * CCH * 2;           // 128 KB (We16)
    const size_t VB = (size_t)BATCH * NM * 4;          // 64 KB

    size_t off = 0;
    auto alloc = [&](size_t bytes) {
        char* p = ws + off;
        off += (bytes + 255) & ~(size_t)255;
        return p;
    };
    short* W16_1 = (short*)alloc(WB);
    short* W16_2 = (short*)alloc(WB);
    short* We16  = (short*)alloc(EB);
    short* Xt16  = (short*)alloc(SB);   // in1^T (b,p,c)
    short* Qt16  = (short*)alloc(SB);   // in2^T (b,p,c)
    short* E16n  = (short*)alloc(SB);   // (b,n,d)
    short* eattT = (short*)alloc(SB);
    short* qattT = (short*)alloc(SB);
    short* X16   = (short*)alloc(SB);   // in1 (b,c,p) bf16
    short* Q16   = (short*)alloc(SB);   // in2 (b,c,p) bf16
    float* m1v   = (float*)alloc(VB);
    float* m2v   = (float*)alloc(VB);

    const int nW = CCH * 2 * CCH;
    const int nWe = CCH * CCH;

    k_cast<<<dim3(nW / 1024), 256, 0, stream>>>(W1, W16_1, nW);
    k_cast<<<dim3(nW / 1024), 256, 0, stream>>>(W2, W16_2, nW);
    k_cast<<<dim3(nWe / 1024), 256, 0, stream>>>(We, We16, nWe);
    k_prep<<<dim3(HW / 64, CCH / 64, 8), 256, 0, stream>>>(in1, in2, X16, Q16,
                                                           Xt16, Qt16);

    k_E_mfma<<<dim3(2, 32, BATCH), 256, 0, stream>>>(Xt16, We16, E16n);

    k_fused<<<dim3((HW / 64) * 8), 256, 0, stream>>>(E16n, Qt16, Q16, X16, gw,
                                                     eattT, qattT, m1v, m2v);

    k_final<<<dim3(64, 2, 8), 256, 0, stream>>>(W16_1, W16_2, eattT, qattT,
                                                Xt16, Qt16, m1v, m2v, out);
}